// Round 4
// baseline (1996.688 us; speedup 1.0000x reference)
//
#include <hip/hip_runtime.h>
#include <hip/hip_bf16.h>

#define DEVINL __device__ __forceinline__

constexpr int Bb = 8;
constexpr int Nn = 10000;
constexpr int Ff = 256;     // F (K dim of GEMM)
constexpr int Hh = 128;     // H (N dim of GEMM)
constexpr int Ee = 320000;
constexpr int Mm = Bb * Nn; // 80000 GEMM rows

constexpr int CHUNK = 64;                     // rows per bucket
constexpr int NCH = (Nn + CHUNK - 1) / CHUNK; // 157 buckets/batch
constexpr int CAP = 2560;                     // bucket capacity (mean 2048, 11 sigma)
constexpr int GPB = 40;                       // scatter workgroups per batch
constexpr int EPG = Ee / GPB;                 // 8000 edges per workgroup

typedef __attribute__((ext_vector_type(8))) short short8;
typedef __attribute__((ext_vector_type(4))) float float4v;
typedef __attribute__((ext_vector_type(4))) unsigned short ushort4v;

DEVINL float b2f(unsigned short s) {
    unsigned int u = ((unsigned int)s) << 16;
    float f;
    __builtin_memcpy(&f, &u, 4);
    return f;
}
DEVINL unsigned short f2b(float f) {
    unsigned int u;
    __builtin_memcpy(&u, &f, 4);
    unsigned int r = (u + 0x7fffu + ((u >> 16) & 1u)) >> 16;
    return (unsigned short)r;
}
DEVINL float i2f(int i) {
    float f;
    __builtin_memcpy(&f, &i, 4);
    return f;
}

// ---------------- weight transpose+convert: w[K][H] fp32 -> wT[H][K] bf16 ----
__global__ void transpose_w_kernel(const float* __restrict__ w,
                                   unsigned short* __restrict__ wT) {
    int idx = blockIdx.x * blockDim.x + threadIdx.x;
    if (idx >= Ff * Hh) return;
    int h = idx / Ff, k = idx % Ff;
    wT[idx] = f2b(w[(size_t)k * Hh + h]);
}

// ---------------- coarse bucket binning (privatized histogram + append) ------
// record: .x = col | (row&63)<<20, .y = fp32 val bits
__global__ __launch_bounds__(256) void bucket_kernel(const int* __restrict__ rows,
                                                     const int* __restrict__ cols,
                                                     const float* __restrict__ vals,
                                                     int* __restrict__ cur,
                                                     int2* __restrict__ bkt) {
    __shared__ int lcnt[NCH];
    __shared__ int lbase[NCH];
    int b = blockIdx.x / GPB, g = blockIdx.x % GPB;
    int t = threadIdx.x;
    const int base = b * Ee + g * EPG;

    for (int j = t; j < NCH; j += 256) lcnt[j] = 0;
    __syncthreads();
    for (int i = t; i < EPG; i += 256)
        atomicAdd(&lcnt[rows[base + i] >> 6], 1);
    __syncthreads();
    for (int j = t; j < NCH; j += 256)
        lbase[j] = atomicAdd(&cur[b * NCH + j], lcnt[j]);
    __syncthreads();
    for (int j = t; j < NCH; j += 256) lcnt[j] = 0;
    __syncthreads();
    for (int i = t; i < EPG; i += 256) {
        int r = rows[base + i];
        int bk = r >> 6;
        int off = atomicAdd(&lcnt[bk], 1);
        int pos = lbase[bk] + off;
        if (pos < CAP) {
            int c = cols[base + i];
            float vf = vals[base + i];
            int vb;
            __builtin_memcpy(&vb, &vf, 4);
            bkt[(size_t)(b * NCH + bk) * CAP + pos] = make_int2(c | ((r & 63) << 20), vb);
        }
    }
}

// ---------------- fused dropout + GEMM (LDS-staged bf16 MFMA) ----------------
__global__ __launch_bounds__(256, 3) void gemm_kernel(const float* __restrict__ x,
                                                      const float* __restrict__ u,
                                                      const unsigned short* __restrict__ wT,
                                                      unsigned short* __restrict__ xw) {
    __shared__ unsigned short sA[64 * 136];
    __shared__ unsigned short sB[128 * 136];
    int t = threadIdx.x;
    int wave = t >> 6, lane = t & 63;
    int n = lane & 15, q = lane >> 4;
    int m0 = blockIdx.x * 64;

    float4v acc[8];
#pragma unroll
    for (int i = 0; i < 8; i++) acc[i] = {0.f, 0.f, 0.f, 0.f};

    for (int kh = 0; kh < 2; kh++) {
#pragma unroll
        for (int i = 0; i < 8; i++) {
            int idx = t + i * 256;
            int row = idx >> 5;
            int c4 = idx & 31;
            const float* xp = x + (size_t)(m0 + row) * Ff + kh * 128 + c4 * 4;
            const float* up = u + (size_t)(m0 + row) * Ff + kh * 128 + c4 * 4;
            float4 xv = *(const float4*)xp;
            float4 uv = *(const float4*)up;
            ushort4v a;
            a.x = f2b(uv.x > 0.5f ? xv.x * 2.0f : 0.0f);
            a.y = f2b(uv.y > 0.5f ? xv.y * 2.0f : 0.0f);
            a.z = f2b(uv.z > 0.5f ? xv.z * 2.0f : 0.0f);
            a.w = f2b(uv.w > 0.5f ? xv.w * 2.0f : 0.0f);
            *(ushort4v*)(&sA[row * 136 + c4 * 4]) = a;
        }
#pragma unroll
        for (int i = 0; i < 8; i++) {
            int idx = t + i * 256;
            int h = idx >> 4;
            int kc = idx & 15;
            short8 bv = *(const short8*)(wT + (size_t)h * Ff + kh * 128 + kc * 8);
            *(short8*)(&sB[h * 136 + kc * 8]) = bv;
        }
        __syncthreads();
#pragma unroll
        for (int k0 = 0; k0 < 128; k0 += 32) {
            short8 af = *(const short8*)(&sA[(wave * 16 + n) * 136 + k0 + q * 8]);
#pragma unroll
            for (int tt = 0; tt < 8; tt++) {
                short8 bf = *(const short8*)(&sB[(tt * 16 + n) * 136 + k0 + q * 8]);
                acc[tt] = __builtin_amdgcn_mfma_f32_16x16x32_bf16(af, bf, acc[tt], 0, 0, 0);
            }
        }
        __syncthreads();
    }
#pragma unroll
    for (int tt = 0; tt < 8; tt++) {
#pragma unroll
        for (int r = 0; r < 4; r++) {
            int row = m0 + wave * 16 + q * 4 + r;
            int col = tt * 16 + n;
            xw[(size_t)row * Hh + col] = f2b(acc[tt][r]);
        }
    }
}

// ---------------- SpMM: one block per 64-row chunk, LDS fp32 accumulate ------
__global__ __launch_bounds__(256) void spmm_kernel(const int* __restrict__ cur,
                                                   const int2* __restrict__ bkt,
                                                   const unsigned short* __restrict__ xw,
                                                   float* __restrict__ out) {
    __shared__ float accum[CHUNK * Hh];   // 32 KB
    int blk = blockIdx.x;
    int b = blk / NCH, ch = blk % NCH;
    int t = threadIdx.x, w = t >> 6, lane = t & 63;

    for (int j = t; j < CHUNK * Hh; j += 256)
        accum[j] = 0.f;
    __syncthreads();

    int cnt = cur[blk];
    const int2* pe = bkt + (size_t)blk * CAP;
    const unsigned short* xwb = xw + (size_t)b * Nn * Hh;

    int ntiles = (cnt + 63) >> 6;
    for (int tt = w; tt < ntiles; tt += 4) {
        int e0 = tt << 6;
        int2 e = make_int2(0, 0);          // pad: col 0, row 0, val +0.0f (no-op)
        if (e0 + lane < cnt) e = pe[e0 + lane];
#pragma unroll 8
        for (int j = 0; j < 64; j++) {
            int p = __builtin_amdgcn_readlane(e.x, j);
            float v = i2f(__builtin_amdgcn_readlane(e.y, j));
            int c = p & 0xFFFF;
            int rl = p >> 20;
            float x0 = b2f(xwb[(size_t)c * Hh + lane]);
            float x1 = b2f(xwb[(size_t)c * Hh + 64 + lane]);
            atomicAdd(&accum[rl * Hh + lane], v * x0);        // bank = lane%32, 2-way free
            atomicAdd(&accum[rl * Hh + 64 + lane], v * x1);
        }
    }
    __syncthreads();

    int r0 = ch * CHUNK;
    for (int j = t; j < CHUNK * 32; j += 256) {
        int rr = j >> 5;
        int r = r0 + rr;
        if (r < Nn)
            *(float4*)(out + ((size_t)b * Nn + r) * Hh + (j & 31) * 4) =
                *(float4*)&accum[j * 4];
    }
}

extern "C" void kernel_launch(void* const* d_in, const int* in_sizes, int n_in,
                              void* d_out, int out_size, void* d_ws, size_t ws_size,
                              hipStream_t stream) {
    const float* x    = (const float*)d_in[0]; // fp32 [B,N,F]
    const float* du   = (const float*)d_in[1]; // fp32 [B,N,F]
    const int*   rows = (const int*)d_in[2];   // int32 [B,E]
    const int*   cols = (const int*)d_in[3];   // int32 [B,E]
    const float* vals = (const float*)d_in[4]; // fp32 [B,E]
    const float* w    = (const float*)d_in[5]; // fp32 [F,H]
    float*       out  = (float*)d_out;         // fp32 [B,N,H]

    char* p = (char*)d_ws;
    unsigned short* xw = (unsigned short*)p; p += (size_t)Mm * Hh * 2;   // 20.48 MB
    unsigned short* wT = (unsigned short*)p; p += (size_t)Ff * Hh * 2;   // 64 KB
    int* cur   = (int*)p; p += (size_t)Bb * NCH * 4;                     // 5 KB
    int2* bkt  = (int2*)p; p += (size_t)Bb * NCH * CAP * 8;              // 25.7 MB

    hipMemsetAsync(cur, 0, (size_t)Bb * NCH * 4, stream);
    transpose_w_kernel<<<(Ff * Hh + 255) / 256, 256, 0, stream>>>(w, wT);
    bucket_kernel<<<Bb * GPB, 256, 0, stream>>>(rows, cols, vals, cur, bkt);
    gemm_kernel<<<Mm / 64, 256, 0, stream>>>(x, du, wT, xw);
    spmm_kernel<<<Bb * NCH, 256, 0, stream>>>(cur, bkt, xw, out);
}

// Round 5
// 357.858 us; speedup vs baseline: 5.5796x; 5.5796x over previous
//
#include <hip/hip_runtime.h>
#include <hip/hip_bf16.h>

#define DEVINL __device__ __forceinline__

constexpr int Bb = 8;
constexpr int Nn = 10000;
constexpr int Ff = 256;     // F (K dim of GEMM)
constexpr int Hh = 128;     // H (N dim of GEMM)
constexpr int Ee = 320000;
constexpr int Mm = Bb * Nn; // 80000 GEMM rows

constexpr int CHUNK = 64;                     // rows per bucket
constexpr int NCH = (Nn + CHUNK - 1) / CHUNK; // 157 buckets/batch
constexpr int CAP = 2560;                     // bucket capacity (mean 2048, 11 sigma)
constexpr int GPB = 40;                       // binning workgroups per batch
constexpr int EPG = Ee / GPB;                 // 8000 edges per workgroup

typedef __attribute__((ext_vector_type(8))) short short8;
typedef __attribute__((ext_vector_type(4))) float float4v;
typedef __attribute__((ext_vector_type(4))) unsigned short ushort4v;

DEVINL float b2f(unsigned short s) {
    unsigned int u = ((unsigned int)s) << 16;
    float f;
    __builtin_memcpy(&f, &u, 4);
    return f;
}
DEVINL unsigned short f2b(float f) {
    unsigned int u;
    __builtin_memcpy(&u, &f, 4);
    unsigned int r = (u + 0x7fffu + ((u >> 16) & 1u)) >> 16;
    return (unsigned short)r;
}
DEVINL float i2f(int i) {
    float f;
    __builtin_memcpy(&f, &i, 4);
    return f;
}

// ---------------- weight transpose+convert: w[K][H] fp32 -> wT[H][K] bf16 ----
__global__ void transpose_w_kernel(const float* __restrict__ w,
                                   unsigned short* __restrict__ wT) {
    int idx = blockIdx.x * blockDim.x + threadIdx.x;
    if (idx >= Ff * Hh) return;
    int h = idx / Ff, k = idx % Ff;
    wT[idx] = f2b(w[(size_t)k * Hh + h]);
}

// ---------------- coarse bucket binning (privatized histogram + append) ------
// record: .x = col | (row&63)<<20, .y = fp32 val bits  (int LDS atomics only)
__global__ __launch_bounds__(256) void bucket_kernel(const int* __restrict__ rows,
                                                     const int* __restrict__ cols,
                                                     const float* __restrict__ vals,
                                                     int* __restrict__ cur,
                                                     int2* __restrict__ bkt) {
    __shared__ int lcnt[NCH];
    __shared__ int lbase[NCH];
    int b = blockIdx.x / GPB, g = blockIdx.x % GPB;
    int t = threadIdx.x;
    const int base = b * Ee + g * EPG;

    for (int j = t; j < NCH; j += 256) lcnt[j] = 0;
    __syncthreads();
    for (int i = t; i < EPG; i += 256)
        atomicAdd(&lcnt[rows[base + i] >> 6], 1);
    __syncthreads();
    for (int j = t; j < NCH; j += 256)
        lbase[j] = atomicAdd(&cur[b * NCH + j], lcnt[j]);
    __syncthreads();
    for (int j = t; j < NCH; j += 256) lcnt[j] = 0;
    __syncthreads();
    for (int i = t; i < EPG; i += 256) {
        int r = rows[base + i];
        int bk = r >> 6;
        int off = atomicAdd(&lcnt[bk], 1);
        int pos = lbase[bk] + off;
        if (pos < CAP) {
            int c = cols[base + i];
            float vf = vals[base + i];
            int vb;
            __builtin_memcpy(&vb, &vf, 4);
            bkt[(size_t)(b * NCH + bk) * CAP + pos] = make_int2(c | ((r & 63) << 20), vb);
        }
    }
}

// ---------------- fused dropout + GEMM (LDS-staged bf16 MFMA) ----------------
__global__ __launch_bounds__(256, 3) void gemm_kernel(const float* __restrict__ x,
                                                      const float* __restrict__ u,
                                                      const unsigned short* __restrict__ wT,
                                                      unsigned short* __restrict__ xw) {
    __shared__ unsigned short sA[64 * 136];
    __shared__ unsigned short sB[128 * 136];
    int t = threadIdx.x;
    int wave = t >> 6, lane = t & 63;
    int n = lane & 15, q = lane >> 4;
    int m0 = blockIdx.x * 64;

    float4v acc[8];
#pragma unroll
    for (int i = 0; i < 8; i++) acc[i] = {0.f, 0.f, 0.f, 0.f};

    for (int kh = 0; kh < 2; kh++) {
#pragma unroll
        for (int i = 0; i < 8; i++) {
            int idx = t + i * 256;
            int row = idx >> 5;
            int c4 = idx & 31;
            const float* xp = x + (size_t)(m0 + row) * Ff + kh * 128 + c4 * 4;
            const float* up = u + (size_t)(m0 + row) * Ff + kh * 128 + c4 * 4;
            float4 xv = *(const float4*)xp;
            float4 uv = *(const float4*)up;
            ushort4v a;
            a.x = f2b(uv.x > 0.5f ? xv.x * 2.0f : 0.0f);
            a.y = f2b(uv.y > 0.5f ? xv.y * 2.0f : 0.0f);
            a.z = f2b(uv.z > 0.5f ? xv.z * 2.0f : 0.0f);
            a.w = f2b(uv.w > 0.5f ? xv.w * 2.0f : 0.0f);
            *(ushort4v*)(&sA[row * 136 + c4 * 4]) = a;
        }
#pragma unroll
        for (int i = 0; i < 8; i++) {
            int idx = t + i * 256;
            int h = idx >> 4;
            int kc = idx & 15;
            short8 bv = *(const short8*)(wT + (size_t)h * Ff + kh * 128 + kc * 8);
            *(short8*)(&sB[h * 136 + kc * 8]) = bv;
        }
        __syncthreads();
#pragma unroll
        for (int k0 = 0; k0 < 128; k0 += 32) {
            short8 af = *(const short8*)(&sA[(wave * 16 + n) * 136 + k0 + q * 8]);
#pragma unroll
            for (int tt = 0; tt < 8; tt++) {
                short8 bf = *(const short8*)(&sB[(tt * 16 + n) * 136 + k0 + q * 8]);
                acc[tt] = __builtin_amdgcn_mfma_f32_16x16x32_bf16(af, bf, acc[tt], 0, 0, 0);
            }
        }
        __syncthreads();
    }
#pragma unroll
    for (int tt = 0; tt < 8; tt++) {
#pragma unroll
        for (int r = 0; r < 4; r++) {
            int row = m0 + wave * 16 + q * 4 + r;
            int col = tt * 16 + n;
            xw[(size_t)row * Hh + col] = f2b(acc[tt][r]);
        }
    }
}

// ---------------- SpMM: bucket -> LDS row-sort (int atomics) -> reg MLP ------
__global__ __launch_bounds__(256) void spmm_kernel(const int* __restrict__ cur,
                                                   const int2* __restrict__ bkt,
                                                   const unsigned short* __restrict__ xw,
                                                   float* __restrict__ out) {
    __shared__ int2 sedge[CAP];       // 20.5 KB sorted edges
    __shared__ int scnt[CHUNK];
    __shared__ int soff[CHUNK];
    __shared__ int scur[CHUNK];
    int blk = blockIdx.x;
    int b = blk / NCH, ch = blk % NCH;
    int t = threadIdx.x, w = t >> 6, lane = t & 63;

    if (t < CHUNK) scnt[t] = 0;
    __syncthreads();
    int cnt = cur[blk];
    if (cnt > CAP) cnt = CAP;
    const int2* pe = bkt + (size_t)blk * CAP;

    // phase 1: per-row histogram (int LDS atomics — native ds_add)
    for (int i = t; i < cnt; i += 256)
        atomicAdd(&scnt[pe[i].x >> 20], 1);
    __syncthreads();
    // phase 2: exclusive scan over 64 rows (wave 0, shfl)
    if (w == 0) {
        int v = scnt[lane];
        int s = v;
#pragma unroll
        for (int d = 1; d < 64; d <<= 1) {
            int o = __shfl_up(s, d);
            if (lane >= d) s += o;
        }
        soff[lane] = s - v;
        scur[lane] = s - v;
    }
    __syncthreads();
    // phase 3: scatter into row-sorted LDS order (int LDS atomics)
    for (int i = t; i < cnt; i += 256) {
        int2 e = pe[i];
        int pos = atomicAdd(&scur[e.x >> 20], 1);
        sedge[pos] = e;
    }
    __syncthreads();

    // phase 4: each wave owns 16 rows; register MLP-8 accumulate
    const unsigned short* xwb = xw + (size_t)b * Nn * Hh;
    for (int rr = 0; rr < 16; rr++) {
        int rl = w * 16 + rr;
        int r = ch * CHUNK + rl;
        if (r >= Nn) break;
        int off = soff[rl];
        int rcnt = scnt[rl];

        float a0[8], a1[8];
#pragma unroll
        for (int k = 0; k < 8; k++) { a0[k] = 0.f; a1[k] = 0.f; }

        for (int c0 = 0; c0 < rcnt; c0 += 64) {
            int rem = rcnt - c0;
            if (rem > 64) rem = 64;
            int2 e = make_int2(0, 0);           // pad: col 0, val +0.0f (no-op)
            if (lane < rem) e = sedge[off + c0 + lane];
            int rrp = (rem + 7) & ~7;
            for (int j = 0; j < rrp; j += 8) {
#pragma unroll
                for (int k = 0; k < 8; k++) {
                    int c = __builtin_amdgcn_readlane(e.x, j + k) & 0xFFFFF;
                    float v = i2f(__builtin_amdgcn_readlane(e.y, j + k));
                    unsigned int two = *(const unsigned int*)(xwb + (size_t)c * Hh + lane * 2);
                    a0[k] += v * b2f((unsigned short)(two & 0xffffu));
                    a1[k] += v * b2f((unsigned short)(two >> 16));
                }
            }
        }
        float s0 = ((a0[0] + a0[1]) + (a0[2] + a0[3])) + ((a0[4] + a0[5]) + (a0[6] + a0[7]));
        float s1 = ((a1[0] + a1[1]) + (a1[2] + a1[3])) + ((a1[4] + a1[5]) + (a1[6] + a1[7]));
        float2 res;
        res.x = s0;
        res.y = s1;
        *(float2*)(out + ((size_t)b * Nn + r) * Hh + lane * 2) = res;
    }
}

extern "C" void kernel_launch(void* const* d_in, const int* in_sizes, int n_in,
                              void* d_out, int out_size, void* d_ws, size_t ws_size,
                              hipStream_t stream) {
    const float* x    = (const float*)d_in[0]; // fp32 [B,N,F]
    const float* du   = (const float*)d_in[1]; // fp32 [B,N,F]
    const int*   rows = (const int*)d_in[2];   // int32 [B,E]
    const int*   cols = (const int*)d_in[3];   // int32 [B,E]
    const float* vals = (const float*)d_in[4]; // fp32 [B,E]
    const float* w    = (const float*)d_in[5]; // fp32 [F,H]
    float*       out  = (float*)d_out;         // fp32 [B,N,H]

    char* p = (char*)d_ws;
    unsigned short* xw = (unsigned short*)p; p += (size_t)Mm * Hh * 2;   // 20.48 MB
    unsigned short* wT = (unsigned short*)p; p += (size_t)Ff * Hh * 2;   // 64 KB
    int* cur   = (int*)p; p += (size_t)Bb * NCH * 4;                     // 5 KB
    int2* bkt  = (int2*)p; p += (size_t)Bb * NCH * CAP * 8;              // 25.7 MB

    hipMemsetAsync(cur, 0, (size_t)Bb * NCH * 4, stream);
    transpose_w_kernel<<<(Ff * Hh + 255) / 256, 256, 0, stream>>>(w, wT);
    bucket_kernel<<<Bb * GPB, 256, 0, stream>>>(rows, cols, vals, cur, bkt);
    gemm_kernel<<<Mm / 64, 256, 0, stream>>>(x, du, wT, xw);
    spmm_kernel<<<Bb * NCH, 256, 0, stream>>>(cur, bkt, xw, out);
}